// Round 1
// baseline (8994.893 us; speedup 1.0000x reference)
//
#include <hip/hip_runtime.h>
#include <math.h>

// Problem constants
#define B_    2
#define S_    2048
#define H_    4096
#define NH_   32
#define NKV_  2
#define HD_   128
#define ROT_  64
#define GQ_   16            // NH / NKV
#define NQKV_ 4608          // (NH + 2*NKV) * HD
#define M_    4096          // B * S
#define SCALE_ 0.088388347648318447f  // 1/sqrt(128)

// ---------------------------------------------------------------------------
// SGEMM: C = A @ B (+ bias), A: MxK row-major, B: KxN row-major, fp32.
// 128x128 block tile, BK=8, 256 threads, 8x8 micro-tile per thread.
// ---------------------------------------------------------------------------
__global__ __launch_bounds__(256) void sgemm_kernel(
    const float* __restrict__ A, const float* __restrict__ Bm,
    const float* __restrict__ bias, float* __restrict__ C,
    int M, int N, int K)
{
  __shared__ __align__(16) float As[8][128];   // [k][m] (transposed on store)
  __shared__ __align__(16) float Bs[8][128];   // [k][n]
  const int tid = threadIdx.x;
  const int bm = blockIdx.y * 128;
  const int bn = blockIdx.x * 128;
  const int tx = tid & 15;        // col group (8 cols)
  const int ty = tid >> 4;        // row group (8 rows)
  const int a_row = tid >> 1;             // 0..127
  const int a_col = (tid & 1) * 4;        // 0 or 4
  const int b_row = tid >> 5;             // 0..7
  const int b_col = (tid & 31) * 4;       // 0..124

  const float* Ag = A + (size_t)(bm + a_row) * K + a_col;
  const float* Bg = Bm + (size_t)b_row * N + bn + b_col;

  float acc[8][8];
#pragma unroll
  for (int i = 0; i < 8; ++i)
#pragma unroll
    for (int j = 0; j < 8; ++j) acc[i][j] = 0.0f;

  for (int k0 = 0; k0 < K; k0 += 8) {
    float4 av = *(const float4*)(Ag + k0);
    float4 bv = *(const float4*)(Bg + (size_t)k0 * N);
    As[a_col + 0][a_row] = av.x;
    As[a_col + 1][a_row] = av.y;
    As[a_col + 2][a_row] = av.z;
    As[a_col + 3][a_row] = av.w;
    *(float4*)&Bs[b_row][b_col] = bv;
    __syncthreads();
#pragma unroll
    for (int kk = 0; kk < 8; ++kk) {
      float4 a0 = *(float4*)&As[kk][ty * 8];
      float4 a1 = *(float4*)&As[kk][ty * 8 + 4];
      float4 b0 = *(float4*)&Bs[kk][tx * 8];
      float4 b1 = *(float4*)&Bs[kk][tx * 8 + 4];
      float ar[8] = {a0.x, a0.y, a0.z, a0.w, a1.x, a1.y, a1.z, a1.w};
      float br[8] = {b0.x, b0.y, b0.z, b0.w, b1.x, b1.y, b1.z, b1.w};
#pragma unroll
      for (int i = 0; i < 8; ++i)
#pragma unroll
        for (int j = 0; j < 8; ++j)
          acc[i][j] = fmaf(ar[i], br[j], acc[i][j]);
    }
    __syncthreads();
  }

  float4 bb0 = make_float4(0.f, 0.f, 0.f, 0.f);
  float4 bb1 = make_float4(0.f, 0.f, 0.f, 0.f);
  if (bias) {
    bb0 = *(const float4*)(bias + bn + tx * 8);
    bb1 = *(const float4*)(bias + bn + tx * 8 + 4);
  }
#pragma unroll
  for (int i = 0; i < 8; ++i) {
    int row = bm + ty * 8 + i;
    float* dst = C + (size_t)row * N + bn + tx * 8;
    float4 o0, o1;
    o0.x = acc[i][0] + bb0.x; o0.y = acc[i][1] + bb0.y;
    o0.z = acc[i][2] + bb0.z; o0.w = acc[i][3] + bb0.w;
    o1.x = acc[i][4] + bb1.x; o1.y = acc[i][5] + bb1.y;
    o1.z = acc[i][6] + bb1.z; o1.w = acc[i][7] + bb1.w;
    *(float4*)dst = o0;
    *(float4*)(dst + 4) = o1;
  }
}

// ---------------------------------------------------------------------------
// RoPE (GLM interleaved, first ROT dims of each q and k head), in-place.
// pair p rotates (2p, 2p+1) by angle pos / 10000^(p/32).
// ---------------------------------------------------------------------------
__global__ __launch_bounds__(256) void rope_kernel(
    float* __restrict__ qkv, const int* __restrict__ positions)
{
  int t = blockIdx.x * blockDim.x + threadIdx.x;
  const int total = M_ * (NH_ + NKV_) * (ROT_ / 2);
  if (t >= total) return;
  int pair = t & 31;                      // ROT/2 = 32
  int hh   = (t >> 5) % (NH_ + NKV_);     // 0..33 (32 q heads, 2 k heads)
  int tok  = t / (32 * (NH_ + NKV_));
  int col  = hh * HD_;                    // q heads at 0.., k heads right after at 4096..
  float pos  = (float)positions[tok];
  float freq = powf(10000.0f, -(float)pair * (1.0f / 32.0f));
  float ang  = pos * freq;
  float s = sinf(ang), c = cosf(ang);
  size_t base = (size_t)tok * NQKV_ + col + 2 * pair;
  float x1 = qkv[base], x2 = qkv[base + 1];
  qkv[base]     = x1 * c - x2 * s;
  qkv[base + 1] = x1 * s + x2 * c;
}

// ---------------------------------------------------------------------------
// Flash attention, fp32, causal, GQA (q head h uses kv head h/16).
// One block = 32 query rows of one (b, h); K-tiles of 64 with online softmax.
// ---------------------------------------------------------------------------
#define QT_  32
#define KT_  64
#define HDP_ 132   // HD + 4 pad (break stride-128 bank aliasing)
#define KTP_ 65    // KT + 1 pad

__global__ __launch_bounds__(256) void flash_kernel(
    const float* __restrict__ qkv, float* __restrict__ out)
{
  __shared__ __align__(16) float Qs[QT_][HDP_];
  __shared__ __align__(16) float KVs[KT_][HDP_];
  __shared__ float Ss[QT_][KTP_];
  __shared__ float m_s[QT_], l_s[QT_], al_s[QT_];

  const int tid = threadIdx.x;
  const int q0  = blockIdx.x * QT_;
  const int b   = blockIdx.y / NH_;
  const int h   = blockIdx.y % NH_;
  const int g   = h / GQ_;
  const size_t tok0 = (size_t)b * S_;

  // Load Q tile (32 x 128)
  for (int i = tid; i < QT_ * (HD_ / 4); i += 256) {
    int r = i >> 5;            // / 32
    int c = (i & 31) << 2;
    *(float4*)&Qs[r][c] =
        *(const float4*)(qkv + (tok0 + q0 + r) * NQKV_ + h * HD_ + c);
  }
  if (tid < QT_) { m_s[tid] = -INFINITY; l_s[tid] = 0.0f; }

  float o[16];
#pragma unroll
  for (int c = 0; c < 16; ++c) o[c] = 0.0f;
  const int orow = tid >> 3;          // 0..31
  const int ocol = (tid & 7) << 4;    // 0,16,..,112
  __syncthreads();

  const int kend = q0 + QT_;          // exclusive causal key bound for this tile
  for (int kt = 0; kt < kend; kt += KT_) {
    // K tile
    for (int i = tid; i < KT_ * (HD_ / 4); i += 256) {
      int r = i >> 5, c = (i & 31) << 2;
      *(float4*)&KVs[r][c] =
          *(const float4*)(qkv + (tok0 + kt + r) * NQKV_ + NH_ * HD_ + g * HD_ + c);
    }
    __syncthreads();

    // Scores: thread -> row r = tid/8, 8 keys j0..j0+7
    {
      const int r  = tid >> 3;
      const int j0 = (tid & 7) << 3;
      float sc[8];
#pragma unroll
      for (int j = 0; j < 8; ++j) sc[j] = 0.0f;
      for (int c = 0; c < HD_; c += 4) {
        float4 qv = *(float4*)&Qs[r][c];
#pragma unroll
        for (int j = 0; j < 8; ++j) {
          float4 kv = *(float4*)&KVs[j0 + j][c];
          sc[j] += qv.x * kv.x + qv.y * kv.y + qv.z * kv.z + qv.w * kv.w;
        }
      }
#pragma unroll
      for (int j = 0; j < 8; ++j) {
        int key = kt + j0 + j;
        Ss[r][j0 + j] = (key <= q0 + r) ? sc[j] * SCALE_ : -INFINITY;
      }
    }
    __syncthreads();

    // Online softmax row pass (threads 0..31, one row each)
    if (tid < QT_) {
      const int r = tid;
      float m_old = m_s[r];
      float mx = m_old;
      for (int j = 0; j < KT_; ++j) mx = fmaxf(mx, Ss[r][j]);
      float alpha = (m_old == -INFINITY) ? 0.0f : __expf(m_old - mx);
      float sum = 0.0f;
      for (int j = 0; j < KT_; ++j) {
        float p = __expf(Ss[r][j] - mx);   // exp(-inf) = 0 handles masked
        Ss[r][j] = p;
        sum += p;
      }
      l_s[r] = l_s[r] * alpha + sum;
      m_s[r] = mx;
      al_s[r] = alpha;
    }
    __syncthreads();

    // V tile (reuse KVs buffer)
    for (int i = tid; i < KT_ * (HD_ / 4); i += 256) {
      int r = i >> 5, c = (i & 31) << 2;
      *(float4*)&KVs[r][c] =
          *(const float4*)(qkv + (tok0 + kt + r) * NQKV_ + (NH_ + NKV_) * HD_ + g * HD_ + c);
    }
    __syncthreads();

    // O rescale + P @ V accumulate (thread owns row orow, 16 cols at ocol)
    {
      float alpha = al_s[orow];
#pragma unroll
      for (int c = 0; c < 16; ++c) o[c] *= alpha;
      for (int j = 0; j < KT_; ++j) {
        float p = Ss[orow][j];
#pragma unroll
        for (int c = 0; c < 16; ++c)
          o[c] = fmaf(p, KVs[j][ocol + c], o[c]);
      }
    }
    __syncthreads();
  }

  float inv_l = 1.0f / l_s[orow];
  float* dst = out + (tok0 + q0 + orow) * H_ + h * HD_ + ocol;
#pragma unroll
  for (int c = 0; c < 16; ++c) dst[c] = o[c] * inv_l;
}

// ---------------------------------------------------------------------------
extern "C" void kernel_launch(void* const* d_in, const int* in_sizes, int n_in,
                              void* d_out, int out_size, void* d_ws, size_t ws_size,
                              hipStream_t stream)
{
  (void)in_sizes; (void)n_in; (void)out_size;
  const float* hidden    = (const float*)d_in[0];
  const float* w_qkv     = (const float*)d_in[1];
  const float* b_qkv     = (const float*)d_in[2];
  const float* w_dense   = (const float*)d_in[3];
  const int*   positions = (const int*)d_in[4];
  float* out = (float*)d_out;

  const size_t qkv_bytes  = (size_t)M_ * NQKV_ * sizeof(float);  // 75.5 MB
  const size_t attn_bytes = (size_t)M_ * H_ * sizeof(float);     // 67.1 MB
  float* qkv = (float*)d_ws;
  const bool roomy = ws_size >= qkv_bytes + attn_bytes;
  float* attn      = roomy ? (float*)((char*)d_ws + qkv_bytes) : out;
  float* dense_dst = roomy ? out : (float*)d_ws;  // !roomy: reuse qkv region, copy back

  // 1) qkv = hidden @ w_qkv + b_qkv
  sgemm_kernel<<<dim3(NQKV_ / 128, M_ / 128), 256, 0, stream>>>(
      hidden, w_qkv, b_qkv, qkv, M_, NQKV_, H_);

  // 2) RoPE in-place on q (32 heads) + k (2 heads)
  {
    int total = M_ * (NH_ + NKV_) * (ROT_ / 2);
    rope_kernel<<<(total + 255) / 256, 256, 0, stream>>>(qkv, positions);
  }

  // 3) causal GQA flash attention
  flash_kernel<<<dim3(S_ / QT_, B_ * NH_), 256, 0, stream>>>(qkv, attn);

  // 4) out = attn @ w_dense
  sgemm_kernel<<<dim3(H_ / 128, M_ / 128), 256, 0, stream>>>(
      attn, w_dense, nullptr, dense_dst, M_, H_, H_);

  if (!roomy) {
    hipMemcpyAsync(out, dense_dst, attn_bytes, hipMemcpyDeviceToDevice, stream);
  }
}

// Round 3
// 4293.182 us; speedup vs baseline: 2.0952x; 2.0952x over previous
//
#include <hip/hip_runtime.h>
#include <math.h>

// Problem constants
#define B_    2
#define S_    2048
#define H_    4096
#define NH_   32
#define NKV_  2
#define HD_   128
#define ROT_  64
#define GQ_   16            // NH / NKV
#define NQKV_ 4608          // (NH + 2*NKV) * HD
#define M_    4096          // B * S
#define SCALE_ 0.088388347648318447f  // 1/sqrt(128)

typedef __attribute__((ext_vector_type(8))) short s16x8;
typedef __attribute__((ext_vector_type(4))) float f32x4;

__device__ __forceinline__ unsigned short f2bf(float x) {
  union { float f; unsigned u; } v; v.f = x;
  unsigned r = (v.u + 0x7fffu + ((v.u >> 16) & 1u)) >> 16;
  return (unsigned short)r;
}

// ---------------------------------------------------------------------------
// SGEMM: C = A @ B (+ bias), fp32, 128x128 tile, BK=8, 8x8 micro-tile.
// ---------------------------------------------------------------------------
__global__ __launch_bounds__(256) void sgemm_kernel(
    const float* __restrict__ A, const float* __restrict__ Bm,
    const float* __restrict__ bias, float* __restrict__ C,
    int M, int N, int K)
{
  __shared__ __align__(16) float As[8][128];
  __shared__ __align__(16) float Bs[8][128];
  const int tid = threadIdx.x;
  const int bm = blockIdx.y * 128;
  const int bn = blockIdx.x * 128;
  const int tx = tid & 15;
  const int ty = tid >> 4;
  const int a_row = tid >> 1;
  const int a_col = (tid & 1) * 4;
  const int b_row = tid >> 5;
  const int b_col = (tid & 31) * 4;

  const float* Ag = A + (size_t)(bm + a_row) * K + a_col;
  const float* Bg = Bm + (size_t)b_row * N + bn + b_col;

  float acc[8][8];
#pragma unroll
  for (int i = 0; i < 8; ++i)
#pragma unroll
    for (int j = 0; j < 8; ++j) acc[i][j] = 0.0f;

  for (int k0 = 0; k0 < K; k0 += 8) {
    float4 av = *(const float4*)(Ag + k0);
    float4 bv = *(const float4*)(Bg + (size_t)k0 * N);
    As[a_col + 0][a_row] = av.x;
    As[a_col + 1][a_row] = av.y;
    As[a_col + 2][a_row] = av.z;
    As[a_col + 3][a_row] = av.w;
    *(float4*)&Bs[b_row][b_col] = bv;
    __syncthreads();
#pragma unroll
    for (int kk = 0; kk < 8; ++kk) {
      float4 a0 = *(float4*)&As[kk][ty * 8];
      float4 a1 = *(float4*)&As[kk][ty * 8 + 4];
      float4 b0 = *(float4*)&Bs[kk][tx * 8];
      float4 b1 = *(float4*)&Bs[kk][tx * 8 + 4];
      float ar[8] = {a0.x, a0.y, a0.z, a0.w, a1.x, a1.y, a1.z, a1.w};
      float br[8] = {b0.x, b0.y, b0.z, b0.w, b1.x, b1.y, b1.z, b1.w};
#pragma unroll
      for (int i = 0; i < 8; ++i)
#pragma unroll
        for (int j = 0; j < 8; ++j)
          acc[i][j] = fmaf(ar[i], br[j], acc[i][j]);
    }
    __syncthreads();
  }

  float4 bb0 = make_float4(0.f, 0.f, 0.f, 0.f);
  float4 bb1 = make_float4(0.f, 0.f, 0.f, 0.f);
  if (bias) {
    bb0 = *(const float4*)(bias + bn + tx * 8);
    bb1 = *(const float4*)(bias + bn + tx * 8 + 4);
  }
#pragma unroll
  for (int i = 0; i < 8; ++i) {
    int row = bm + ty * 8 + i;
    float* dst = C + (size_t)row * N + bn + tx * 8;
    float4 o0, o1;
    o0.x = acc[i][0] + bb0.x; o0.y = acc[i][1] + bb0.y;
    o0.z = acc[i][2] + bb0.z; o0.w = acc[i][3] + bb0.w;
    o1.x = acc[i][4] + bb1.x; o1.y = acc[i][5] + bb1.y;
    o1.z = acc[i][6] + bb1.z; o1.w = acc[i][7] + bb1.w;
    *(float4*)dst = o0;
    *(float4*)(dst + 4) = o1;
  }
}

// ---------------------------------------------------------------------------
// RoPE (GLM interleaved, first ROT dims of q and k heads), in-place fp32.
// ---------------------------------------------------------------------------
__global__ __launch_bounds__(256) void rope_kernel(
    float* __restrict__ qkv, const int* __restrict__ positions)
{
  int t = blockIdx.x * blockDim.x + threadIdx.x;
  const int total = M_ * (NH_ + NKV_) * (ROT_ / 2);
  if (t >= total) return;
  int pair = t & 31;
  int hh   = (t >> 5) % (NH_ + NKV_);
  int tok  = t / (32 * (NH_ + NKV_));
  int col  = hh * HD_;
  float pos  = (float)positions[tok];
  float freq = powf(10000.0f, -(float)pair * (1.0f / 32.0f));
  float ang  = pos * freq;
  float s = sinf(ang), c = cosf(ang);
  size_t base = (size_t)tok * NQKV_ + col + 2 * pair;
  float x1 = qkv[base], x2 = qkv[base + 1];
  qkv[base]     = x1 * c - x2 * s;
  qkv[base + 1] = x1 * s + x2 * c;
}

// ---------------------------------------------------------------------------
// V transpose + bf16 convert: vt[bg][c][s] <- qkv V part [b][s][g*128+c].
// 64x64 tiles through LDS; bg = b*NKV + g.
// ---------------------------------------------------------------------------
__global__ __launch_bounds__(256) void vtrans_kernel(
    const float* __restrict__ qkv, unsigned short* __restrict__ vt)
{
  __shared__ __align__(16) unsigned short T[64][72];
  const int tid = threadIdx.x;
  const int s0 = blockIdx.x * 64;
  const int c0 = blockIdx.y * 64;
  const int bg = blockIdx.z;
  const int b = bg >> 1, g = bg & 1;

#pragma unroll
  for (int i = 0; i < 4; ++i) {
    int idx = tid + i * 256;
    int sr = idx >> 4;             // 0..63 (token within tile)
    int cc = (idx & 15) << 2;      // 0..60 step 4
    const float* p = qkv + (size_t)(b * S_ + s0 + sr) * NQKV_
                     + (NH_ + NKV_) * HD_ + g * HD_ + c0 + cc;
    float4 v = *(const float4*)p;
    T[cc + 0][sr] = f2bf(v.x);
    T[cc + 1][sr] = f2bf(v.y);
    T[cc + 2][sr] = f2bf(v.z);
    T[cc + 3][sr] = f2bf(v.w);
  }
  __syncthreads();
#pragma unroll
  for (int i = 0; i < 2; ++i) {
    int idx = tid + i * 256;
    int cr = idx >> 3;             // 0..63
    int kc = idx & 7;              // 16B chunk within 64 tokens
    s16x8 v = *(const s16x8*)&T[cr][kc << 3];
    *(s16x8*)&vt[(size_t)((bg << 7) + c0 + cr) * S_ + s0 + (kc << 3)] = v;
  }
}

// ---------------------------------------------------------------------------
// Flash attention, bf16 MFMA, causal, GQA.
// Block: 64 q-rows of one (b,h), 4 waves (16 rows each), K-tiles of 64.
// LDS (uint16 elements):
//   [0, 8704)        Ks[key][e], stride 136 (2-way conflicts only)
//   [8704, 16896)    Vt[col][key] 64 keys/row, XOR-chunk swizzle (also Qs at init)
//   [16896, 21504)   Ps[4 waves][16 rows][stride 72]
// ---------------------------------------------------------------------------
#define QS_OFF 8704
#define VT_OFF 8704
#define PS_OFF 16896

__global__ __launch_bounds__(256) void flash_mfma_kernel(
    const float* __restrict__ qkv, const unsigned short* __restrict__ vt,
    float* __restrict__ out)
{
  __shared__ __align__(16) unsigned short smem[21504];

  const int tid  = threadIdx.x;
  const int lane = tid & 63;
  const int w    = tid >> 6;        // wave 0..3
  const int quad = lane >> 4;       // 0..3
  const int l15  = lane & 15;
  const int q0 = blockIdx.x * 64;
  const int b  = blockIdx.y >> 5;
  const int h  = blockIdx.y & 31;
  const int g  = h >> 4;
  const int bg = b * NKV_ + g;
  const size_t tok0 = (size_t)b * S_;

  // ---- Stage Q (64x128 = 2048 float4-chunks, fold in softmax scale) ----
#pragma unroll
  for (int i = 0; i < 8; ++i) {          // FIX: was 4 — rows 32..63 were never staged
    int idx = tid + i * 256;
    int r = idx >> 5, c4 = (idx & 31) << 2;
    const float* p = qkv + (tok0 + q0 + r) * NQKV_ + h * HD_ + c4;
    float4 v = *(const float4*)p;
    ushort4 o;
    o.x = f2bf(v.x * SCALE_); o.y = f2bf(v.y * SCALE_);
    o.z = f2bf(v.z * SCALE_); o.w = f2bf(v.w * SCALE_);
    *(ushort4*)&smem[QS_OFF + r * 136 + c4] = o;
  }
  __syncthreads();

  // Q fragments: A-operand, m = l15 (row within wave's 16), k = quad*8 + ks*32 + j
  s16x8 qf[4];
#pragma unroll
  for (int ks = 0; ks < 4; ++ks)
    qf[ks] = *(const s16x8*)&smem[QS_OFF + (w * 16 + l15) * 136 + (quad << 3) + (ks << 5)];
  __syncthreads();  // all waves done reading Qs before Vt overwrites it

  f32x4 O[8];
#pragma unroll
  for (int n = 0; n < 8; ++n)
#pragma unroll
    for (int i = 0; i < 4; ++i) O[n][i] = 0.0f;
  float m_i[4] = {-INFINITY, -INFINITY, -INFINITY, -INFINITY};
  float l_i[4] = {0.f, 0.f, 0.f, 0.f};

  for (int kt = 0; kt <= q0; kt += 64) {
    // ---- Stage K tile (64x128 = 2048 float4-chunks, fp32 -> bf16) ----
#pragma unroll
    for (int i = 0; i < 8; ++i) {        // FIX: was 4 — keys 32..63 were never staged
      int idx = tid + i * 256;
      int key = idx >> 5, c4 = (idx & 31) << 2;
      const float* p = qkv + (tok0 + kt + key) * NQKV_ + NH_ * HD_ + g * HD_ + c4;
      float4 v = *(const float4*)p;
      ushort4 o;
      o.x = f2bf(v.x); o.y = f2bf(v.y); o.z = f2bf(v.z); o.w = f2bf(v.w);
      *(ushort4*)&smem[key * 136 + c4] = o;
    }
    // ---- Stage V tile from pre-transposed bf16 (col-major, chunk swizzle) ----
#pragma unroll
    for (int i = 0; i < 4; ++i) {
      int idx = tid + i * 256;
      int c = idx >> 3, kc = idx & 7;
      s16x8 v = *(const s16x8*)&vt[(size_t)((bg << 7) + c) * S_ + kt + (kc << 3)];
      *(s16x8*)&smem[VT_OFF + (c << 6) + (((kc + c) & 7) << 3)] = v;
    }
    __syncthreads();

    // ---- S = Q K^T (4 n-tiles of 16 keys, K=128 over 4 MFMA steps) ----
    f32x4 S[4];
#pragma unroll
    for (int nt = 0; nt < 4; ++nt) {
#pragma unroll
      for (int i = 0; i < 4; ++i) S[nt][i] = 0.0f;
#pragma unroll
      for (int ks = 0; ks < 4; ++ks) {
        s16x8 kf = *(const s16x8*)&smem[(nt * 16 + l15) * 136 + (quad << 3) + (ks << 5)];
        S[nt] = __builtin_amdgcn_mfma_f32_16x16x32_bf16(qf[ks], kf, S[nt], 0, 0, 0);
      }
    }

    // ---- causal mask on diagonal tile ----
    if (kt == q0) {
#pragma unroll
      for (int nt = 0; nt < 4; ++nt) {
        int colL = nt * 16 + l15;
#pragma unroll
        for (int i = 0; i < 4; ++i) {
          int rowL = w * 16 + quad * 4 + i;
          if (colL > rowL) S[nt][i] = -INFINITY;
        }
      }
    }

    // ---- online softmax (rows = quad*4+i, reduce over l15 lanes + nt) ----
    float mx[4], alpha[4], rs[4];
#pragma unroll
    for (int i = 0; i < 4; ++i) {
      mx[i] = fmaxf(fmaxf(S[0][i], S[1][i]), fmaxf(S[2][i], S[3][i]));
#pragma unroll
      for (int off = 1; off < 16; off <<= 1)
        mx[i] = fmaxf(mx[i], __shfl_xor(mx[i], off));
      float mn = fmaxf(m_i[i], mx[i]);
      alpha[i] = __expf(m_i[i] - mn);   // exp(-inf) = 0 on first tile
      m_i[i] = mn;
      rs[i] = 0.0f;
    }
#pragma unroll
    for (int nt = 0; nt < 4; ++nt)
#pragma unroll
      for (int i = 0; i < 4; ++i) {
        float p = __expf(S[nt][i] - m_i[i]);
        S[nt][i] = p;
        rs[i] += p;
      }
#pragma unroll
    for (int i = 0; i < 4; ++i) {
#pragma unroll
      for (int off = 1; off < 16; off <<= 1)
        rs[i] += __shfl_xor(rs[i], off);
      l_i[i] = l_i[i] * alpha[i] + rs[i];
    }

    // ---- write P (bf16) to per-wave LDS, C-layout -> A-layout transform ----
#pragma unroll
    for (int nt = 0; nt < 4; ++nt)
#pragma unroll
      for (int i = 0; i < 4; ++i)
        smem[PS_OFF + (w * 16 + quad * 4 + i) * 72 + nt * 16 + l15] = f2bf(S[nt][i]);

    // ---- rescale O ----
#pragma unroll
    for (int n = 0; n < 8; ++n)
#pragma unroll
      for (int i = 0; i < 4; ++i) O[n][i] *= alpha[i];

    __syncthreads();  // Ps visible (and keeps waves off next staging)

    // ---- O += P V ----
    s16x8 pf[2];
#pragma unroll
    for (int ks2 = 0; ks2 < 2; ++ks2)
      pf[ks2] = *(const s16x8*)&smem[PS_OFF + (w * 16 + l15) * 72 + (quad << 3) + (ks2 << 5)];
#pragma unroll
    for (int nt2 = 0; nt2 < 8; ++nt2) {
      int col = nt2 * 16 + l15;
#pragma unroll
      for (int ks2 = 0; ks2 < 2; ++ks2) {
        int kc = ks2 * 4 + quad;
        s16x8 vf = *(const s16x8*)&smem[VT_OFF + (col << 6) + (((kc + col) & 7) << 3)];
        O[nt2] = __builtin_amdgcn_mfma_f32_16x16x32_bf16(pf[ks2], vf, O[nt2], 0, 0, 0);
      }
    }
    __syncthreads();  // done with Ks/Vt before next tile's staging
  }

  // ---- epilogue: O / l, write fp32 ----
  float inv[4];
#pragma unroll
  for (int i = 0; i < 4; ++i) inv[i] = 1.0f / l_i[i];
#pragma unroll
  for (int nt2 = 0; nt2 < 8; ++nt2)
#pragma unroll
    for (int i = 0; i < 4; ++i) {
      size_t row = tok0 + q0 + w * 16 + quad * 4 + i;
      out[row * H_ + h * HD_ + nt2 * 16 + l15] = O[nt2][i] * inv[i];
    }
}

// ---------------------------------------------------------------------------
extern "C" void kernel_launch(void* const* d_in, const int* in_sizes, int n_in,
                              void* d_out, int out_size, void* d_ws, size_t ws_size,
                              hipStream_t stream)
{
  (void)in_sizes; (void)n_in; (void)out_size;
  const float* hidden    = (const float*)d_in[0];
  const float* w_qkv     = (const float*)d_in[1];
  const float* b_qkv     = (const float*)d_in[2];
  const float* w_dense   = (const float*)d_in[3];
  const int*   positions = (const int*)d_in[4];
  float* out = (float*)d_out;

  const size_t qkv_bytes  = (size_t)M_ * NQKV_ * sizeof(float);          // 75.5 MB
  const size_t vt_bytes   = (size_t)B_ * NKV_ * HD_ * S_ * sizeof(short);// 2 MB
  const size_t attn_bytes = (size_t)M_ * H_ * sizeof(float);             // 67.1 MB

  float* qkv          = (float*)d_ws;
  unsigned short* vt  = (unsigned short*)((char*)d_ws + qkv_bytes);
  const bool roomy = ws_size >= qkv_bytes + vt_bytes + attn_bytes;
  float* attn      = roomy ? (float*)((char*)d_ws + qkv_bytes + vt_bytes) : out;
  float* dense_dst = roomy ? out : (float*)d_ws;  // !roomy: reuse qkv region

  // 1) qkv = hidden @ w_qkv + b_qkv
  sgemm_kernel<<<dim3(NQKV_ / 128, M_ / 128), 256, 0, stream>>>(
      hidden, w_qkv, b_qkv, qkv, M_, NQKV_, H_);

  // 2) RoPE in-place
  {
    int total = M_ * (NH_ + NKV_) * (ROT_ / 2);
    rope_kernel<<<(total + 255) / 256, 256, 0, stream>>>(qkv, positions);
  }

  // 3) V transpose + bf16
  vtrans_kernel<<<dim3(S_ / 64, HD_ / 64, B_ * NKV_), 256, 0, stream>>>(qkv, vt);

  // 4) causal GQA flash attention (bf16 MFMA)
  flash_mfma_kernel<<<dim3(S_ / 64, B_ * NH_), 256, 0, stream>>>(qkv, vt, attn);

  // 5) out = attn @ w_dense
  sgemm_kernel<<<dim3(H_ / 128, M_ / 128), 256, 0, stream>>>(
      attn, w_dense, nullptr, dense_dst, M_, H_, H_);

  if (!roomy) {
    hipMemcpyAsync(out, dense_dst, attn_bytes, hipMemcpyDeviceToDevice, stream);
  }
}